// Round 11
// baseline (127.965 us; speedup 1.0000x reference)
//
#include <hip/hip_runtime.h>

// B=8, C=64, H=W=64, CI=32, N=4096 pixels, M=1024 pooled.
// y[b,n,:] = (a_n*S1[k_n,:] + S2[k_n,:])/1024 ; only W_w . y is needed, so
// track U = Ww.psi (64-dim) and its sorted-order prefixes T1/T2 directly.
// BN stats from per-k scalars (cnt, sum a, sum a^2) x T rows - no Gram.
//
// r16: attack kA's 80% idle (1 block/CU -> CU stalls at every barrier) and
// the cross-XCD T write amplification (r10: WRITE 22MB, 8 XCDs partial-
// writeback each 64B line). (1) kA = 512 blocks x 512 threads, 2/CU:
// co-resident blocks are from DIFFERENT batches, so per-batch barrier
// spins overlap with the other batch's compute. (2) batch->XCD affinity:
// blockIdx = work*8 + b in both kernels (round-robin %8 heuristic) -- all
// writers/readers of batch b share one XCD's L2: partial-line T stores
// merge (full-line writeback), kB's T reads fetched once then L2-hot.
// (3) T1/T2 interleaved as float2 T12[b][k][o]: halves lines touched.
// Skeleton unchanged from r10: 2 kernels split at the global sync, sc1
// only for intra-kA cross-block data, plain stores for kB-consumed data.
#define OFF_A    0         // a[b][n]               : 32768 floats
#define OFF_BB   32768     // bb[b][m]              : 8192
#define OFF_RK   40960     // rank[b][m] (int)      : 8192
#define OFF_U    57344     // U_T[b][o][m]          : 8*64*1024 = 524288
#define OFF_T12  581632    // T12[b][k<=1024][o] f2 : 8*1025*64*2 = 1049600
#define OFF_KK   1631232   // k[b][n] (int)         : 32768
#define OFF_MP1  1664000   // moment1 partials [b][o] : 512
#define OFF_MP2  1664512   // moment2 partials [b][o] : 512
#define OFF_HC   1665024   // hist cnt[b][1025]     : 8200
#define OFF_HS   1673224   // hist sum_a[b][1025]   : 8200
#define OFF_HS2  1681424   // hist sum_a2[b][1025]  : 8200
#define OFF_BAR  1689624   // u32: batch b ctr @32*(b+1); flags @288,289

// Coherent (sc1, L2-bypass) helpers -- intra-kA cross-block data only.
__device__ __forceinline__ void stg(float* p, float v) {
    __hip_atomic_store(p, v, __ATOMIC_RELAXED, __HIP_MEMORY_SCOPE_AGENT);
}
__device__ __forceinline__ float ldg1(const float* p) {
    return __hip_atomic_load(p, __ATOMIC_RELAXED, __HIP_MEMORY_SCOPE_AGENT);
}
__device__ __forceinline__ void stgi(int* p, int v) {
    __hip_atomic_store(p, v, __ATOMIC_RELAXED, __HIP_MEMORY_SCOPE_AGENT);
}
__device__ __forceinline__ int ldgi(const int* p) {
    return __hip_atomic_load(p, __ATOMIC_RELAXED, __HIP_MEMORY_SCOPE_AGENT);
}
__device__ __forceinline__ void stgu(unsigned* p, unsigned v) {
    __hip_atomic_store(p, v, __ATOMIC_RELAXED, __HIP_MEMORY_SCOPE_AGENT);
}
__device__ __forceinline__ unsigned ldgu(const unsigned* p) {
    return __hip_atomic_load(p, __ATOMIC_RELAXED, __HIP_MEMORY_SCOPE_AGENT);
}

// kA LDS carve (floats), one 6932-float block (27.7 KB, 2 blocks/CU):
// P1: sm[0..4160) sth[4160..4228) spsi[4228..4756) sWw[4756..6868)
// P2: sb[0..1024)
// P3: ssb[0..1024) sU[1024..2048) shc[2048..3073) shs[3073..4098)
//     shs2[4098..5123) swp1[5123..5131) swp2[5131..5139)
// persistent P1->P2: sA2[6868..6932) -- this block's 64 a-values
__global__ __launch_bounds__(512) void kA(
    const float* __restrict__ x, const float* __restrict__ theta_w,
    const float* __restrict__ theta_b, const float* __restrict__ phi_w,
    const float* __restrict__ phi_b, const float* __restrict__ psi_w,
    const float* __restrict__ psi_b, const float* __restrict__ cp_w,
    const float* __restrict__ Ww, float* __restrict__ ws)
{
    __shared__ float sh[6932];
    const int tid = threadIdx.x;
    const int bid = blockIdx.x;
    const int b   = bid & 7;      // batch -> XCD (round-robin %8)
    const int sub = bid >> 3;     // 0..63 within batch
    unsigned* bars = (unsigned*)(ws + OFF_BAR);
    float* sA2 = sh + 6868;

    // ---------- Phase 1: phi/psi conv+pool -> bb, U_T ; theta -> a --------
    {
        if (bid == 0 && tid == 0) {     // zero 8 batch counters (sc1)
            for (int i = 0; i < 8; ++i) stgu(&bars[(i + 1) << 5], 0u);
        }
        // zero this block's slice of ITS OWN batch's hist (3075/64 -> 49)
        if (tid < 49) {
            int e = sub*49 + tid;
            if (e < 1025)      stg(&ws[OFF_HC  + b*1025 + e], 0.0f);
            else if (e < 2050) stg(&ws[OFF_HS  + b*1025 + e - 1025], 0.0f);
            else if (e < 3075) stg(&ws[OFF_HS2 + b*1025 + e - 2050], 0.0f);
        }
        float* sm   = sh;          // 32 i-rows x 130: interleaved {phi,psi}
        float* sth  = sh + 4160;   // tw_eff[64] + tb_eff
        float* spsi = sh + 4228;   // 16 m-rows x 32 i (pad 33)
        float* sWw  = sh + 4756;   // 64 o-rows x 32 i (pad 33)
        for (int e = tid; e < 2048; e += 512) {
            int i = e >> 6, c = e & 63;
            sm[i*130 + 2*c]     = phi_w[e];
            sm[i*130 + 2*c + 1] = psi_w[e];
        }
        for (int e = tid; e < 2048; e += 512)
            sWw[(e >> 5)*33 + (e & 31)] = Ww[(e >> 5)*33 + (e & 31)];
        if (tid < 64) {
            float s = 0;
            for (int i = 0; i < 32; ++i) s += cp_w[i]*theta_w[i*64 + tid];
            sth[tid] = s;
        } else if (tid == 64) {
            float s = 0;
            for (int i = 0; i < 32; ++i) s += cp_w[i]*theta_b[i];
            sth[64] = s;
        }
        __syncthreads();   // drains vmcnt -> counter zeros at MALL
        if (bid == 0 && tid == 0) {    // publish ready flags (poison-proof)
            stgu(&bars[288], 0x5A5A5A5Au);
            stgu(&bars[289], 0xA5A5A5A5u);
        }
        int i = tid & 31;
        int mIdx = tid >> 5;                 // 0..15
        int m = (sub << 4) + mIdx;
        int ph = m >> 5, pw = m & 31;
        const float* xb = x + b*262144 + ph*128 + pw*2;
        const float2* wrow = (const float2*)(sm + i*130);
        float tb = sth[64];
        float p0=0,p1=0,p2=0,p3=0,s0=0,s1=0,s2=0,s3=0;
        float a0=tb,a1=tb,a2=tb,a3=tb;       // theta: bias-first like before
        #pragma unroll 8
        for (int c = 0; c < 64; ++c) {
            float2 xa = *(const float2*)(xb + c*4096);
            float2 xc = *(const float2*)(xb + c*4096 + 64);
            float2 w  = wrow[c];             // {phi_w, psi_w}
            float st  = sth[c];              // broadcast read
            p0 += xa.x*w.x; p1 += xa.y*w.x; p2 += xc.x*w.x; p3 += xc.y*w.x;
            s0 += xa.x*w.y; s1 += xa.y*w.y; s2 += xc.x*w.y; s3 += xc.y*w.y;
            a0 += xa.x*st;  a1 += xa.y*st;  a2 += xc.x*st;  a3 += xc.y*st;
        }
        float pv = fmaxf(fmaxf(p0,p1), fmaxf(p2,p3)) + phi_b[i];
        float sv = fmaxf(fmaxf(s0,s1), fmaxf(s2,s3)) + psi_b[i];
        spsi[mIdx*33 + i] = sv;
        float v = pv * cp_w[32 + i];
        v += __shfl_xor(v, 16, 32);
        v += __shfl_xor(v,  8, 32);
        v += __shfl_xor(v,  4, 32);
        v += __shfl_xor(v,  2, 32);
        v += __shfl_xor(v,  1, 32);
        if (i == 0) {
            stg(&ws[OFF_BB + (b<<10) + m], v);   // sc1: read in P2/P3
            int nb = (b<<12) + ph*128 + pw*2;    // pixel (2ph,2pw)
            ws[OFF_A + nb]      = a0;            // plain: kB only
            ws[OFF_A + nb + 1]  = a1;
            ws[OFF_A + nb + 64] = a2;
            ws[OFF_A + nb + 65] = a3;
            int pwl = pw & 15;                   // local (this block's 64)
            sA2[pwl*2]      = a0;                // LDS: P2 reads these
            sA2[pwl*2 + 1]  = a1;
            sA2[32 + pwl*2]     = a2;
            sA2[32 + pwl*2 + 1] = a3;
        }
        __syncthreads();
        // U-loop: idx = (o, ml): 16 consecutive lanes store 64B per o (sc1)
        #pragma unroll
        for (int rep = 0; rep < 2; ++rep) {
            int idx = tid + (rep << 9);         // 0..1023 = 64 o x 16 ml
            int o  = idx >> 4;
            int ml = idx & 15;
            const float* pr = &spsi[ml*33];
            const float* wr = &sWw[o*33];
            float u = 0;
            #pragma unroll
            for (int i2 = 0; i2 < 32; ++i2) u += pr[i2]*wr[i2];
            stg(&ws[OFF_U + (((b<<6) + o)<<10) + (sub<<4) + ml], u);
        }
    }
    // gen1 (per-batch, 64 arrivals), one-time ready-flag check first
    __syncthreads();
    if (tid == 0) {
        while ((ldgu(&bars[288]) ^ ldgu(&bars[289])) != 0xFFFFFFFFu)
            __builtin_amdgcn_s_sleep(2);
        unsigned* ctr = bars + ((b + 1) << 5);
        __hip_atomic_fetch_add(ctr, 1u, __ATOMIC_RELAXED,
                               __HIP_MEMORY_SCOPE_AGENT);
        while (ldgu(ctr) < 64u) __builtin_amdgcn_s_sleep(2);
    }
    __syncthreads();

    // ---------- Phase 2: rank bb -> RK, k_n per pixel, per-b histogram ----
    {
        float* sb = sh;
        for (int e = tid; e < 1024; e += 512)
            sb[e] = ldg1(&ws[OFF_BB + (b<<10) + e]);
        __syncthreads();
        {   // rank this block's 16 m's (32 lanes per m, integer-exact)
            int ml = tid >> 5, jl = tid & 31;
            int m = (sub << 4) + ml;
            float vv = sb[m];
            int cnt = 0;
            for (int s = 0; s < 32; ++s) {
                int j = jl + (s << 5);
                float u = sb[j];
                cnt += (u > vv || (u == vv && j < m)) ? 1 : 0;
            }
            cnt += __shfl_xor(cnt,  1, 32);
            cnt += __shfl_xor(cnt,  2, 32);
            cnt += __shfl_xor(cnt,  4, 32);
            cnt += __shfl_xor(cnt,  8, 32);
            cnt += __shfl_xor(cnt, 16, 32);
            if (jl == 0)
                stgi(&((int*)ws)[OFF_RK + (b<<10) + m], cnt);  // sc1: P3
        }
        {   // k_n for this block's 64 pixels (8 lanes/pixel) + hist atomics
            int l = tid >> 3, jl = tid & 7;      // l = 0..63
            int row = l >> 5, col = l & 31;
            int phb = sub >> 1, half = sub & 1;
            int n = (2*phb + row)*64 + half*32 + col;
            float av = sA2[row*32 + col];        // own P1 output (LDS)
            float tt = -av;
            const float2* sb2 = (const float2*)sb;
            int cnt = 0;
            for (int s = 0; s < 64; ++s) {
                float2 u = sb2[jl + (s << 3)];   // 8 distinct addrs: free
                cnt += (u.x > tt) ? 1 : 0;
                cnt += (u.y > tt) ? 1 : 0;
            }
            cnt += __shfl_xor(cnt, 1, 8);
            cnt += __shfl_xor(cnt, 2, 8);
            cnt += __shfl_xor(cnt, 4, 8);
            if (jl == 0) {
                ((int*)ws)[OFF_KK + (b<<12) + n] = cnt;  // plain: kB only
                atomicAdd(&ws[OFF_HC + b*1025 + cnt], 1.0f);
                atomicAdd(&ws[OFF_HS + b*1025 + cnt], av);
                atomicAdd(&ws[OFF_HS2 + b*1025 + cnt], av*av);
            }
        }
    }
    // gen2 (per-batch, arrivals reach 128)
    __syncthreads();
    if (tid == 0) {
        unsigned* ctr = bars + ((b + 1) << 5);
        __hip_atomic_fetch_add(ctr, 1u, __ATOMIC_RELAXED,
                               __HIP_MEMORY_SCOPE_AGENT);
        while (ldgu(ctr) < 128u) __builtin_amdgcn_s_sleep(2);
    }
    __syncthreads();

    // ---------- Phase 3: sorted prefixes T12 + BN moment partials --------
    // Block (b, o=sub): ONE output channel. sc1 loads (intra-kA data);
    // T12 float2 o-major plain stores -- all writers of a line are on this
    // XCD (affinity) -> merge in L2, full-line writeback.
    {
        const int o = sub;
        float* ssb  = sh;           // sorted bb
        float* sU   = sh + 1024;    // sorted U for this o
        float* shc  = sh + 2048;
        float* shs  = sh + 3073;
        float* shs2 = sh + 4098;
        float* swp1 = sh + 5123;    // 8 wave partials
        float* swp2 = sh + 5131;
        for (int e = tid; e < 1024; e += 512) {
            float bbv = ldg1(&ws[OFF_BB + (b<<10) + e]);
            int   rk  = ldgi(&((const int*)ws)[OFF_RK + (b<<10) + e]);
            float u   = ldg1(&ws[OFF_U + (((b<<6) + o)<<10) + e]);
            ssb[rk] = bbv;
            sU[rk]  = u;
        }
        for (int e = tid; e < 1025; e += 512) {
            shc[e]  = ldg1(&ws[OFF_HC  + b*1025 + e]);
            shs[e]  = ldg1(&ws[OFF_HS  + b*1025 + e]);
            shs2[e] = ldg1(&ws[OFF_HS2 + b*1025 + e]);
        }
        __syncthreads();
        int ch = tid;                    // 512 chunks x 2 k
        int chl = tid & 63, wv = tid >> 6;
        float p[2], sp[2];
        float s1 = 0, s2 = 0;
        #pragma unroll
        for (int jl = 0; jl < 2; ++jl) {
            int jj = (ch<<1) + jl;
            float v = sU[jj];
            p[jl] = v;
            sp[jl] = ssb[jj]*v;
            s1 += v; s2 += sp[jl];
        }
        float own1 = s1, own2 = s2;
        #pragma unroll
        for (int d = 1; d < 64; d <<= 1) {
            float u1 = __shfl_up(s1, d, 64);
            float u2 = __shfl_up(s2, d, 64);
            if (chl >= d) { s1 += u1; s2 += u2; }
        }
        if (chl == 63) { swp1[wv] = s1; swp2[wv] = s2; }
        __syncthreads();
        float off1 = 0, off2 = 0;
        for (int w = 0; w < 8; ++w) {
            if (w < wv) { off1 += swp1[w]; off2 += swp2[w]; }
        }
        float run1 = off1 + s1 - own1;   // exclusive prefix before chunk ch
        float run2 = off2 + s2 - own2;
        float2* T12 = (float2*)(ws + OFF_T12) + (size_t)b*65600;
        if (ch == 0) T12[o] = make_float2(0.0f, 0.0f);   // k=0 row
        const float inv = 1.0f/1024.0f;
        float m1 = 0, m2 = 0;
        #pragma unroll
        for (int jl = 0; jl < 2; ++jl) {
            int k = (ch<<1) + jl + 1;
            run1 += p[jl]; run2 += sp[jl];
            float t1 = run1*inv, t2 = run2*inv;
            T12[(k<<6) + o] = make_float2(t1, t2);   // plain o-major
            float c = shc[k], sa_ = shs[k], sa2 = shs2[k];
            m1 += sa_*t1 + c*t2;
            m2 += (sa2*t1 + 2.0f*sa_*t2)*t1 + c*t2*t2;
        }
        // reduce moments over the whole block (one o)
        m1 += __shfl_xor(m1,  1, 64); m2 += __shfl_xor(m2,  1, 64);
        m1 += __shfl_xor(m1,  2, 64); m2 += __shfl_xor(m2,  2, 64);
        m1 += __shfl_xor(m1,  4, 64); m2 += __shfl_xor(m2,  4, 64);
        m1 += __shfl_xor(m1,  8, 64); m2 += __shfl_xor(m2,  8, 64);
        m1 += __shfl_xor(m1, 16, 64); m2 += __shfl_xor(m2, 16, 64);
        m1 += __shfl_xor(m1, 32, 64); m2 += __shfl_xor(m2, 32, 64);
        __syncthreads();   // swp reuse
        if (chl == 0) { swp1[wv] = m1; swp2[wv] = m2; }
        __syncthreads();
        if (tid == 0) {
            float a1 = 0, a2 = 0;
            for (int w = 0; w < 8; ++w) { a1 += swp1[w]; a2 += swp2[w]; }
            ws[OFF_MP1 + (b<<6) + o] = a1;     // plain: kB only
            ws[OFF_MP2 + (b<<6) + o] = a2;
        }
    }
    // kernel ends: boundary flush publishes plain data; kB follows.
}

// kB (= P4): out[b,o,n] = A[o]*(a_n*T1[k_n,o]+T2[k_n,o]) + D[o] + x[b,o,n].
// 512 blocks x 512 threads; blockIdx = ng*8 + b -> batch b on XCD b, so
// batch-b's T12 (525KB) is fetched once per XCD then L2-hot.
__global__ __launch_bounds__(512) void kB(
    const float* __restrict__ x, const float* __restrict__ Wb,
    const float* __restrict__ gamma, const float* __restrict__ beta,
    const float* __restrict__ ws, float* __restrict__ out)
{
    __shared__ float tile[64*65];
    __shared__ float sa[64];
    __shared__ int   sk[64];
    __shared__ float sA[64];
    __shared__ float sD[64];
    const int tid = threadIdx.x;
    const int b   = blockIdx.x & 7;
    const int n0  = (blockIdx.x >> 3) << 6;
    if (tid < 64) {
        sa[tid] = ws[OFF_A + (b<<12) + n0 + tid];
        sk[tid] = ((const int*)ws)[OFF_KK + (b<<12) + n0 + tid];
        const float Ninv = 1.0f/32768.0f;
        float m1s = 0, m2s = 0;
        #pragma unroll
        for (int b3 = 0; b3 < 8; ++b3) {
            m1s += ws[OFF_MP1 + (b3<<6) + tid];
            m2s += ws[OFF_MP2 + (b3<<6) + tid];
        }
        float m1 = m1s * Ninv;
        float m2 = m2s * Ninv;
        float wb = Wb[tid];
        float mu  = m1 + wb;
        float E2  = m2 + 2.0f*wb*m1 + wb*wb;
        float var = E2 - mu*mu;
        float A = gamma[tid] * rsqrtf(var + 1e-5f);
        sA[tid] = A;
        sD[tid] = beta[tid] + A*(wb - mu);
    }
    __syncthreads();
    const float2* T12 = (const float2*)(ws + OFF_T12) + (size_t)b*65600;
    {
        int o = tid & 63, ng = tid >> 6;   // 8 waves x 8 n each
        float Ao = sA[o], Do = sD[o];
        #pragma unroll
        for (int j = 0; j < 8; ++j) {
            int n = (ng << 3) + j;
            int k = sk[n];                 // wave-uniform -> coalesced 512B
            float a = sa[n];
            float2 t = T12[(k<<6) + o];
            tile[o*65 + n] = Ao*(a*t.x + t.y) + Do;
        }
    }
    __syncthreads();
    {
        int n = tid & 63, og = tid >> 6;   // 8 groups x 8 o
        #pragma unroll
        for (int j = 0; j < 8; ++j) {
            int o = (og << 3) + j;
            int idx = ((b<<6) + o)*4096 + n0 + n;
            out[idx] = tile[o*65 + n] + x[idx];
        }
    }
}

extern "C" void kernel_launch(void* const* d_in, const int* in_sizes, int n_in,
                              void* d_out, int out_size, void* d_ws, size_t ws_size,
                              hipStream_t stream)
{
    const float* x       = (const float*)d_in[0];
    const float* theta_w = (const float*)d_in[1];
    const float* theta_b = (const float*)d_in[2];
    const float* phi_w   = (const float*)d_in[3];
    const float* phi_b   = (const float*)d_in[4];
    const float* psi_w   = (const float*)d_in[5];
    const float* psi_b   = (const float*)d_in[6];
    const float* cp_w    = (const float*)d_in[7];
    const float* Ww      = (const float*)d_in[8];
    const float* Wb      = (const float*)d_in[9];
    const float* gamma   = (const float*)d_in[10];
    const float* beta    = (const float*)d_in[11];
    float* ws  = (float*)d_ws;
    float* out = (float*)d_out;

    kA<<<512, 512, 0, stream>>>(x, theta_w, theta_b, phi_w, phi_b,
                                psi_w, psi_b, cp_w, Ww, ws);
    kB<<<512, 512, 0, stream>>>(x, Wb, gamma, beta, ws, out);
}

// Round 12
// 115.658 us; speedup vs baseline: 1.1064x; 1.1064x over previous
//
#include <hip/hip_runtime.h>

// B=8, C=64, H=W=64, CI=32, N=4096 pixels, M=1024 pooled.
// y[b,n,:] = (a_n*S1[k_n,:] + S2[k_n,:])/1024 ; only W_w . y is needed, so
// track U = Ww.psi (64-dim) and its sorted-order prefixes T1/T2 directly.
// BN stats from per-k scalars (cnt, sum a, sum a^2) x T rows - no Gram.
//
// r17: P1 conv REWRITTEN as LDS-staged pixel-coalesced GEMM; all else =
// r10 verbatim. Accounting model (fits r0..r11): fixed harness overhead
// ~74us (fill 44 + reset dispatches ~30), kB ~5us, kA ~48us -- and P1 is
// ~35-40 of kA in EVERY variant (r0 kA, r8 k1, r10 fused). Old P1 load
// shape: 128 VMEM/thread, 2 broadcast addrs x 8B useful per instr, 44
// VGPRs -> per-instruction memory-pipe bound. New P1: block stages its
// contiguous 128px x 64c x-slab (32KB, float4 coalesced, 2 ld/thread) +
// W[64c][64f] in LDS; inner loop has ZERO VMEM: 1 b128 broadcast W +
// 2 stride-1 b32 x + 8 FMA per c; wave = filter-group (uniform branch).
// Conv FMA order, pooling max order, bb shuffle order identical to r10
// -> bitwise-identical outputs.
#define OFF_A    0         // a[b][n]               : 32768 floats
#define OFF_BB   32768     // bb[b][m]              : 8192
#define OFF_RK   40960     // rank[b][m] (int)      : 8192
#define OFF_U    57344     // U_T[b][o][m]          : 8*64*1024 = 524288
#define OFF_T1   581632    // T1[b][k<=1024][o]     : 8*1025*64 = 524800
#define OFF_T2   1106432   // T2[b][k][o]           : 524800
#define OFF_KK   1631232   // k[b][n] (int)         : 32768
#define OFF_MP1  1664000   // moment1 partials [b][o] : 512
#define OFF_MP2  1664512   // moment2 partials [b][o] : 512
#define OFF_HC   1665024   // hist cnt[b][1025]     : 8200
#define OFF_HS   1673224   // hist sum_a[b][1025]   : 8200
#define OFF_HS2  1681424   // hist sum_a2[b][1025]  : 8200
#define OFF_BAR  1689624   // u32: batch b ctr @32*(b+1); flags @288,289

// Coherent (sc1, L2-bypass) helpers -- intra-kA cross-block data only.
__device__ __forceinline__ void stg(float* p, float v) {
    __hip_atomic_store(p, v, __ATOMIC_RELAXED, __HIP_MEMORY_SCOPE_AGENT);
}
__device__ __forceinline__ float ldg1(const float* p) {
    return __hip_atomic_load(p, __ATOMIC_RELAXED, __HIP_MEMORY_SCOPE_AGENT);
}
__device__ __forceinline__ void stgi(int* p, int v) {
    __hip_atomic_store(p, v, __ATOMIC_RELAXED, __HIP_MEMORY_SCOPE_AGENT);
}
__device__ __forceinline__ int ldgi(const int* p) {
    return __hip_atomic_load(p, __ATOMIC_RELAXED, __HIP_MEMORY_SCOPE_AGENT);
}
__device__ __forceinline__ void stgu(unsigned* p, unsigned v) {
    __hip_atomic_store(p, v, __ATOMIC_RELAXED, __HIP_MEMORY_SCOPE_AGENT);
}
__device__ __forceinline__ unsigned ldgu(const unsigned* p) {
    return __hip_atomic_load(p, __ATOMIC_RELAXED, __HIP_MEMORY_SCOPE_AGENT);
}

// kA LDS carve (floats), sh[12484] = 49.9 KB:
// P1 conv:  sX@0 (64c x 128px = 8192) sW@8192 (64c x 64f = 4096)
//           sth@12288 (68)  sA2@12356 (128, persists into P2)
// P1 epilo: spsi@0 (32x33) sphi@1056 (32x33) sWw@2112 (64x33) [sX dead]
// P2:       sb@0 (1024)
// P3:       ssb@0 sU0@1024 sU1@2048 shc@3072 shs@4097 shs2@5122
//           swp1@6148 swp2@6180      (all verbatim r10)
__global__ __launch_bounds__(1024) void kA(
    const float* __restrict__ x, const float* __restrict__ theta_w,
    const float* __restrict__ theta_b, const float* __restrict__ phi_w,
    const float* __restrict__ phi_b, const float* __restrict__ psi_w,
    const float* __restrict__ psi_b, const float* __restrict__ cp_w,
    const float* __restrict__ Ww, float* __restrict__ ws)
{
    __shared__ __align__(16) float sh[12484];
    const int tid = threadIdx.x;
    const int bid = blockIdx.x;
    const int b   = bid >> 5;     // 32 blocks per batch image
    const int sub = bid & 31;
    unsigned* bars = (unsigned*)(ws + OFF_BAR);
    float* sX  = sh;
    float* sW  = sh + 8192;
    float* sth = sh + 12288;
    float* sA2 = sh + 12356;

    // ---------- Phase 1: conv (GEMM form) + pool -> bb, U_T ; theta -> a --
    {
        if (bid == 0 && tid == 0) {     // zero 8 batch counters (sc1)
            for (int i = 0; i < 8; ++i) stgu(&bars[(i + 1) << 5], 0u);
        }
        // zero this block's slice of ITS OWN batch's hist (r10 verbatim)
        if (tid < 97) {
            int e = sub*97 + tid;
            if (e < 1025)      stg(&ws[OFF_HC  + b*1025 + e], 0.0f);
            else if (e < 2050) stg(&ws[OFF_HS  + b*1025 + e - 1025], 0.0f);
            else if (e < 3075) stg(&ws[OFF_HS2 + b*1025 + e - 2050], 0.0f);
        }
        // stage x slab: rows 2sub,2sub+1 are CONTIGUOUS (512B per c) ->
        // 2048 float4, fully coalesced, 2 per thread.
        {
            const float4* x4 = (const float4*)x;
            float4* sX4 = (float4*)sX;
            #pragma unroll
            for (int e = tid; e < 2048; e += 1024) {
                int c = e >> 5, off = e & 31;
                sX4[e] = x4[b*65536 + c*1024 + sub*32 + off];
            }
        }
        // stage W[c][f]: f<32 phi, f>=32 psi (reads coalesced; LDS scatter
        // is 64-way on 4 one-time instrs -- negligible).
        #pragma unroll
        for (int e = tid; e < 4096; e += 1024) {
            int f = e >> 6, c = e & 63;
            sW[c*64 + f] = (f < 32) ? phi_w[f*64 + c] : psi_w[(f-32)*64 + c];
        }
        if (tid < 64) {
            float s = 0;
            for (int i = 0; i < 32; ++i) s += cp_w[i]*theta_w[i*64 + tid];
            sth[tid] = s;
        } else if (tid == 64) {
            float s = 0;
            for (int i = 0; i < 32; ++i) s += cp_w[i]*theta_b[i];
            sth[64] = s;
        }
        __syncthreads();   // staging done; drains vmcnt (counter zeros)
        if (bid == 0 && tid == 0) {    // publish ready flags (poison-proof)
            stgu(&bars[288], 0x5A5A5A5Au);
            stgu(&bars[289], 0xA5A5A5A5u);
        }
        const int pxl = tid & 63;      // pixel column
        const int fg  = tid >> 6;      // wave index = filter group (4 f)
        float tb = sth[64];
        float a00=0, a01=0, a02=0, a03=0;   // row 2sub,   filters fg*4..+3
        float a10=0, a11=0, a12=0, a13=0;   // row 2sub+1
        float th0 = tb, th1 = tb;           // theta (fg==0 wave only)
        const float4* sW4 = (const float4*)sW;
        #pragma unroll 8
        for (int c = 0; c < 64; ++c) {
            float x0 = sX[c*128 + pxl];
            float x1 = sX[c*128 + 64 + pxl];
            float4 w = sW4[c*16 + fg];      // wave-uniform: broadcast
            a00 += x0*w.x; a01 += x0*w.y; a02 += x0*w.z; a03 += x0*w.w;
            a10 += x1*w.x; a11 += x1*w.y; a12 += x1*w.z; a13 += x1*w.w;
            if (fg == 0) {                  // wave-uniform branch
                float st = sth[c];
                th0 += x0*st; th1 += x1*st;
            }
        }
        __syncthreads();   // conv reads done -> sX region reusable
        float* spsi = sh;          // 32 m x 33
        float* sphi = sh + 1056;
        float* sWw  = sh + 2112;
        // 2x2 pool: vertical max local, horizontal via shfl_xor(1).
        // max order == r10's fmax(fmax(p0,p1),fmax(p2,p3)) (assoc/comm).
        {
            float v0 = fmaxf(a00, a10), v1 = fmaxf(a01, a11);
            float v2 = fmaxf(a02, a12), v3 = fmaxf(a03, a13);
            float h0 = fmaxf(v0, __shfl_xor(v0, 1, 64));
            float h1 = fmaxf(v1, __shfl_xor(v1, 1, 64));
            float h2 = fmaxf(v2, __shfl_xor(v2, 1, 64));
            float h3 = fmaxf(v3, __shfl_xor(v3, 1, 64));
            if ((pxl & 1) == 0) {
                int ml = pxl >> 1;          // 0..31 pooled column
                int f0 = fg << 2;
                if (fg < 8) {               // phi filters
                    sphi[ml*33 + f0]     = h0 + phi_b[f0];
                    sphi[ml*33 + f0 + 1] = h1 + phi_b[f0 + 1];
                    sphi[ml*33 + f0 + 2] = h2 + phi_b[f0 + 2];
                    sphi[ml*33 + f0 + 3] = h3 + phi_b[f0 + 3];
                } else {                    // psi filters
                    int i0 = f0 - 32;
                    spsi[ml*33 + i0]     = h0 + psi_b[i0];
                    spsi[ml*33 + i0 + 1] = h1 + psi_b[i0 + 1];
                    spsi[ml*33 + i0 + 2] = h2 + psi_b[i0 + 2];
                    spsi[ml*33 + i0 + 3] = h3 + psi_b[i0 + 3];
                }
            }
        }
        if (fg == 0) {     // theta a: 2 pixels per lane, plain stores (kB)
            int nb = (b<<12) + (sub<<7);
            ws[OFF_A + nb + pxl]      = th0;
            ws[OFF_A + nb + 64 + pxl] = th1;
            sA2[pxl]      = th0;            // LDS: P2 reads these
            sA2[64 + pxl] = th1;
        }
        // stage Ww (64 o x 32 i, padded 33) -- r10 verbatim indexing
        #pragma unroll
        for (int e = tid; e < 2048; e += 1024)
            sWw[(e >> 5)*33 + (e & 31)] = Ww[(e >> 5)*33 + (e & 31)];
        __syncthreads();
        // bb reduce from sphi (order == r10: v*w2, shfl 16,8,4,2,1 /32)
        {
            int ml = tid >> 5, il = tid & 31;
            float v = sphi[ml*33 + il] * cp_w[32 + il];
            v += __shfl_xor(v, 16, 32);
            v += __shfl_xor(v,  8, 32);
            v += __shfl_xor(v,  4, 32);
            v += __shfl_xor(v,  2, 32);
            v += __shfl_xor(v,  1, 32);
            if (il == 0)
                stg(&ws[OFF_BB + (b<<10) + (sub<<5) + ml], v);
        }
        // U-loop r10 verbatim: o-major sc1 stores
        #pragma unroll
        for (int rep = 0; rep < 2; ++rep) {
            int o  = (tid >> 5) + (rep << 5);   // 0..63
            int ml = tid & 31;
            const float* pr = &spsi[ml*33];
            const float* wr = &sWw[o*33];
            float u = 0;
            #pragma unroll
            for (int i2 = 0; i2 < 32; ++i2) u += pr[i2]*wr[i2];
            stg(&ws[OFF_U + (((b<<6) + o)<<10) + (sub<<5) + ml], u);
        }
    }
    // gen1 (per-batch), with one-time ready-flag check (r10 verbatim)
    __syncthreads();
    if (tid == 0) {
        while ((ldgu(&bars[288]) ^ ldgu(&bars[289])) != 0xFFFFFFFFu)
            __builtin_amdgcn_s_sleep(2);
        unsigned* ctr = bars + ((b + 1) << 5);
        __hip_atomic_fetch_add(ctr, 1u, __ATOMIC_RELAXED,
                               __HIP_MEMORY_SCOPE_AGENT);
        while (ldgu(ctr) < 32u) __builtin_amdgcn_s_sleep(2);
    }
    __syncthreads();

    // ---------- Phase 2: rank bb -> RK, k_n per pixel, hist (r10 verbatim)
    {
        float* sb = sh;
        sb[tid] = ldg1(&ws[OFF_BB + (b<<10) + tid]);
        __syncthreads();
        {
            int ml = tid >> 5, jl = tid & 31;
            int m = (sub << 5) + ml;
            float vv = sb[m];
            int cnt = 0;
            for (int s = 0; s < 32; ++s) {
                int j = jl + (s << 5);
                float u = sb[j];
                cnt += (u > vv || (u == vv && j < m)) ? 1 : 0;
            }
            cnt += __shfl_xor(cnt,  1, 32);
            cnt += __shfl_xor(cnt,  2, 32);
            cnt += __shfl_xor(cnt,  4, 32);
            cnt += __shfl_xor(cnt,  8, 32);
            cnt += __shfl_xor(cnt, 16, 32);
            if (jl == 0)
                stgi(&((int*)ws)[OFF_RK + (b<<10) + m], cnt);
        }
        {
            int l = tid >> 3, jl = tid & 7;
            int n = (sub << 7) + l;
            float av = sA2[l];
            float tt = -av;
            const float2* sb2 = (const float2*)sb;
            int cnt = 0;
            for (int s = 0; s < 64; ++s) {
                float2 u = sb2[jl + (s << 3)];
                cnt += (u.x > tt) ? 1 : 0;
                cnt += (u.y > tt) ? 1 : 0;
            }
            cnt += __shfl_xor(cnt, 1, 8);
            cnt += __shfl_xor(cnt, 2, 8);
            cnt += __shfl_xor(cnt, 4, 8);
            if (jl == 0) {
                ((int*)ws)[OFF_KK + (b<<12) + n] = cnt;
                atomicAdd(&ws[OFF_HC + b*1025 + cnt], 1.0f);
                atomicAdd(&ws[OFF_HS + b*1025 + cnt], av);
                atomicAdd(&ws[OFF_HS2 + b*1025 + cnt], av*av);
            }
        }
    }
    // gen2 (per-batch) (r10 verbatim)
    __syncthreads();
    if (tid == 0) {
        unsigned* ctr = bars + ((b + 1) << 5);
        __hip_atomic_fetch_add(ctr, 1u, __ATOMIC_RELAXED,
                               __HIP_MEMORY_SCOPE_AGENT);
        while (ldgu(ctr) < 64u) __builtin_amdgcn_s_sleep(2);
    }
    __syncthreads();

    // ---------- Phase 3: sorted prefixes T1/T2 + BN moments (r10 verbatim)
    {
        const int obase = sub << 1;
        float* ssb  = sh;
        float* sU0  = sh + 1024;
        float* sU1  = sh + 2048;
        float* shc  = sh + 3072;
        float* shs  = sh + 4097;
        float* shs2 = sh + 5122;
        float* swp1 = sh + 6148;
        float* swp2 = sh + 6180;
        {
            float bbv = ldg1(&ws[OFF_BB + (b<<10) + tid]);
            int   rk  = ldgi(&((const int*)ws)[OFF_RK + (b<<10) + tid]);
            float u0  = ldg1(&ws[OFF_U + (((b<<6) + obase)<<10) + tid]);
            float u1  = ldg1(&ws[OFF_U + (((b<<6) + obase + 1)<<10) + tid]);
            ssb[rk] = bbv;
            sU0[rk] = u0;
            sU1[rk] = u1;
            shc[tid]  = ldg1(&ws[OFF_HC  + b*1025 + tid]);
            shs[tid]  = ldg1(&ws[OFF_HS  + b*1025 + tid]);
            shs2[tid] = ldg1(&ws[OFF_HS2 + b*1025 + tid]);
            if (tid == 0) {
                shc[1024]  = ldg1(&ws[OFF_HC  + b*1025 + 1024]);
                shs[1024]  = ldg1(&ws[OFF_HS  + b*1025 + 1024]);
                shs2[1024] = ldg1(&ws[OFF_HS2 + b*1025 + 1024]);
            }
        }
        __syncthreads();
        int ch = tid >> 1, o2 = tid & 1;
        int o  = obase + o2;
        int wv = tid >> 6, chl = (tid & 63) >> 1;
        const float* sU = o2 ? sU1 : sU0;
        float p[2], sp[2];
        float s1 = 0, s2 = 0;
        #pragma unroll
        for (int jl = 0; jl < 2; ++jl) {
            int jj = (ch<<1) + jl;
            float v = sU[jj];
            p[jl] = v;
            sp[jl] = ssb[jj]*v;
            s1 += v; s2 += sp[jl];
        }
        float own1 = s1, own2 = s2;
        #pragma unroll
        for (int d = 1; d < 32; d <<= 1) {
            float u1 = __shfl_up(s1, d<<1, 64);
            float u2 = __shfl_up(s2, d<<1, 64);
            if (chl >= d) { s1 += u1; s2 += u2; }
        }
        if (chl == 31) { swp1[(wv<<1)+o2] = s1; swp2[(wv<<1)+o2] = s2; }
        __syncthreads();
        float off1 = 0, off2 = 0;
        for (int w = 0; w < 16; ++w) {
            if (w < wv) { off1 += swp1[(w<<1)+o2]; off2 += swp2[(w<<1)+o2]; }
        }
        float run1 = off1 + s1 - own1;
        float run2 = off2 + s2 - own2;
        float* T1 = ws + OFF_T1 + b*65600;
        float* T2 = ws + OFF_T2 + b*65600;
        if (ch == 0) { T1[o] = 0.0f; T2[o] = 0.0f; }
        const float inv = 1.0f/1024.0f;
        float m1 = 0, m2 = 0;
        #pragma unroll
        for (int jl = 0; jl < 2; ++jl) {
            int k = (ch<<1) + jl + 1;
            run1 += p[jl]; run2 += sp[jl];
            float t1 = run1*inv, t2 = run2*inv;
            T1[(k<<6) + o] = t1;        // plain o-major (L2 absorbs)
            T2[(k<<6) + o] = t2;
            float c = shc[k], sa_ = shs[k], sa2 = shs2[k];
            m1 += sa_*t1 + c*t2;
            m2 += (sa2*t1 + 2.0f*sa_*t2)*t1 + c*t2*t2;
        }
        m1 += __shfl_xor(m1,  2, 64); m2 += __shfl_xor(m2,  2, 64);
        m1 += __shfl_xor(m1,  4, 64); m2 += __shfl_xor(m2,  4, 64);
        m1 += __shfl_xor(m1,  8, 64); m2 += __shfl_xor(m2,  8, 64);
        m1 += __shfl_xor(m1, 16, 64); m2 += __shfl_xor(m2, 16, 64);
        m1 += __shfl_xor(m1, 32, 64); m2 += __shfl_xor(m2, 32, 64);
        __syncthreads();
        if (chl == 0) { swp1[(wv<<1)+o2] = m1; swp2[(wv<<1)+o2] = m2; }
        __syncthreads();
        if (tid < 2) {
            float a1 = 0, a2 = 0;
            for (int w = 0; w < 16; ++w) {
                a1 += swp1[(w<<1)+tid]; a2 += swp2[(w<<1)+tid];
            }
            ws[OFF_MP1 + (b<<6) + obase + tid] = a1;
            ws[OFF_MP2 + (b<<6) + obase + tid] = a2;
        }
    }
}

// kB (= P4): r10 verbatim. out = A[o]*(a_n*T1[k_n,o]+T2[k_n,o])+D[o]+x.
__global__ __launch_bounds__(512) void kB(
    const float* __restrict__ x, const float* __restrict__ Wb,
    const float* __restrict__ gamma, const float* __restrict__ beta,
    const float* __restrict__ ws, float* __restrict__ out)
{
    __shared__ float tile[64*65];
    __shared__ float sa[64];
    __shared__ int   sk[64];
    __shared__ float sA[64];
    __shared__ float sD[64];
    const int tid = threadIdx.x;
    const int b   = blockIdx.x >> 6;
    const int n0  = (blockIdx.x & 63) << 6;
    if (tid < 64) {
        sa[tid] = ws[OFF_A + (b<<12) + n0 + tid];
        sk[tid] = ((const int*)ws)[OFF_KK + (b<<12) + n0 + tid];
        const float Ninv = 1.0f/32768.0f;
        float m1s = 0, m2s = 0;
        #pragma unroll
        for (int b3 = 0; b3 < 8; ++b3) {
            m1s += ws[OFF_MP1 + (b3<<6) + tid];
            m2s += ws[OFF_MP2 + (b3<<6) + tid];
        }
        float m1 = m1s * Ninv;
        float m2 = m2s * Ninv;
        float wb = Wb[tid];
        float mu  = m1 + wb;
        float E2  = m2 + 2.0f*wb*m1 + wb*wb;
        float var = E2 - mu*mu;
        float A = gamma[tid] * rsqrtf(var + 1e-5f);
        sA[tid] = A;
        sD[tid] = beta[tid] + A*(wb - mu);
    }
    __syncthreads();
    const float* T1 = ws + OFF_T1 + b*65600;
    const float* T2 = ws + OFF_T2 + b*65600;
    {
        int o = tid & 63, ng = tid >> 6;
        float Ao = sA[o], Do = sD[o];
        #pragma unroll
        for (int j = 0; j < 8; ++j) {
            int n = (ng << 3) + j;
            int k = sk[n];                 // wave-uniform -> coalesced 256B
            float a = sa[n];
            float t1 = T1[(k<<6) + o];
            float t2 = T2[(k<<6) + o];
            tile[o*65 + n] = Ao*(a*t1 + t2) + Do;
        }
    }
    __syncthreads();
    {
        int n = tid & 63, og = tid >> 6;
        #pragma unroll
        for (int j = 0; j < 8; ++j) {
            int o = (og << 3) + j;
            int idx = ((b<<6) + o)*4096 + n0 + n;
            out[idx] = tile[o*65 + n] + x[idx];
        }
    }
}

extern "C" void kernel_launch(void* const* d_in, const int* in_sizes, int n_in,
                              void* d_out, int out_size, void* d_ws, size_t ws_size,
                              hipStream_t stream)
{
    const float* x       = (const float*)d_in[0];
    const float* theta_w = (const float*)d_in[1];
    const float* theta_b = (const float*)d_in[2];
    const float* phi_w   = (const float*)d_in[3];
    const float* phi_b   = (const float*)d_in[4];
    const float* psi_w   = (const float*)d_in[5];
    const float* psi_b   = (const float*)d_in[6];
    const float* cp_w    = (const float*)d_in[7];
    const float* Ww      = (const float*)d_in[8];
    const float* Wb      = (const float*)d_in[9];
    const float* gamma   = (const float*)d_in[10];
    const float* beta    = (const float*)d_in[11];
    float* ws  = (float*)d_ws;
    float* out = (float*)d_out;

    kA<<<256, 1024, 0, stream>>>(x, theta_w, theta_b, phi_w, phi_b,
                                 psi_w, psi_b, cp_w, Ww, ws);
    kB<<<512, 512, 0, stream>>>(x, Wb, gamma, beta, ws, out);
}